// Round 2
// baseline (559.747 us; speedup 1.0000x reference)
//
#include <hip/hip_runtime.h>
#include <hip/hip_bf16.h>

// ExplodedLogit: out (512, 1 + 512*512) fp32.
//   scores = x @ W.T + b            (512,)
//   idx    = argmax(scores)
//   out[i][0]             = scores[i]
//   out[i][1 + r*512 + j] = scores[i] * (j==idx ? MASK_VAL : 1.0f)
// Output = 537 MB fp32 -> HBM-write-bound, roofline ~85 us @ 6.3 TB/s.

#define TRACKS 512
#define FEATURES 256
#define ROWSTRIDE 262145LL          // 1 + 512*512
#define BULK 262144                 // 512*512
#define MASK_VAL (-105.918914f)     // float32(log(1e-46))

#define BPR 32                      // blocks per row in fill kernel
#define CHUNK (BULK / BPR)          // 8192 elements per block

typedef float vf4 __attribute__((ext_vector_type(4)));  // native vec for nontemporal builtin

// ---- kernel 1: one wave per row dot-product ----
__global__ __launch_bounds__(64) void scores_kernel(
    const float* __restrict__ x, const float* __restrict__ W,
    const float* __restrict__ b, float* __restrict__ scores) {
  int row = blockIdx.x;
  int lane = threadIdx.x;  // 0..63
  const float4* xr = (const float4*)(x + row * FEATURES);
  const float4* wr = (const float4*)W;
  float4 xv = xr[lane];
  float4 wv = wr[lane];
  float s = xv.x * wv.x + xv.y * wv.y + xv.z * wv.z + xv.w * wv.w;
#pragma unroll
  for (int off = 32; off; off >>= 1) s += __shfl_down(s, off);
  if (lane == 0) scores[row] = s + b[0];
}

// ---- kernel 2: argmax (first-index tie-break) + column-0 writes ----
__global__ __launch_bounds__(512) void argmax_kernel(
    const float* __restrict__ scores, int* __restrict__ idx_out,
    float* __restrict__ out) {
  __shared__ float svals[TRACKS];
  __shared__ int sidx[TRACKS];
  int t = threadIdx.x;
  float v = scores[t];
  out[(long long)t * ROWSTRIDE] = v;  // out[i][0] = scores[i]
  svals[t] = v;
  sidx[t] = t;
  __syncthreads();
  for (int off = 256; off; off >>= 1) {
    if (t < off) {
      float v2 = svals[t + off];
      int i2 = sidx[t + off];
      if (v2 > svals[t] || (v2 == svals[t] && i2 < sidx[t])) {
        svals[t] = v2;
        sidx[t] = i2;
      }
    }
    __syncthreads();
  }
  if (t == 0) idx_out[0] = sidx[0];
}

// ---- kernel 3: the 537 MB stream-out ----
// Each block covers CHUNK contiguous elements of one row's bulk region.
// A thread's float4 stores stride by 1024 elements == 0 mod 512 (pattern
// period), so its float4 value is loop-invariant: compute once, store 8x.
__global__ __launch_bounds__(256) void fill_kernel(
    const float* __restrict__ scores, const int* __restrict__ idxp,
    float* __restrict__ out) {
  int row = blockIdx.x >> 5;  // / BPR
  int blk = blockIdx.x & (BPR - 1);
  int t = threadIdx.x;

  float s = scores[row];
  int idx = *idxp;
  float sm = s * MASK_VAL;

  long long S = (long long)row * ROWSTRIDE + 1;  // bulk start (global elems)
  long long lo = S + (long long)blk * CHUNK;

  // scalar head to reach 16B alignment (row stride is odd)
  int align = (int)((4 - (lo & 3)) & 3);
  if (t < align) {
    long long p = lo + t;
    int j = (int)((p - S) & 511);
    out[p] = (j == idx) ? sm : s;
  }

  int nrem = CHUNK - align;
  int nf4 = nrem >> 2;
  int tail = nrem & 3;
  long long abase = lo + align;  // 16B-aligned element offset

  // loop-invariant float4 for this thread
  int j0 = (int)((abase - S + 4 * t) & 511);
  vf4 val;
  val.x = (j0 == idx) ? sm : s;
  val.y = (((j0 + 1) & 511) == idx) ? sm : s;
  val.z = (((j0 + 2) & 511) == idx) ? sm : s;
  val.w = (((j0 + 3) & 511) == idx) ? sm : s;

  vf4* outv = (vf4*)(out + abase);
  for (int k = t; k < nf4; k += 256) {
    __builtin_nontemporal_store(val, &outv[k]);
  }

  // scalar tail
  if (t < tail) {
    long long p = abase + 4LL * nf4 + t;
    int j = (int)((p - S) & 511);
    out[p] = (j == idx) ? sm : s;
  }
}

extern "C" void kernel_launch(void* const* d_in, const int* in_sizes, int n_in,
                              void* d_out, int out_size, void* d_ws,
                              size_t ws_size, hipStream_t stream) {
  const float* x = (const float*)d_in[0];
  const float* W = (const float*)d_in[1];
  const float* b = (const float*)d_in[2];
  float* out = (float*)d_out;

  float* scores = (float*)d_ws;              // 512 floats
  int* idx = (int*)((float*)d_ws + TRACKS);  // 1 int

  scores_kernel<<<TRACKS, 64, 0, stream>>>(x, W, b, scores);
  argmax_kernel<<<1, TRACKS, 0, stream>>>(scores, idx, out);
  fill_kernel<<<TRACKS * BPR, 256, 0, stream>>>(scores, idx, out);
}

// Round 3
// 537.648 us; speedup vs baseline: 1.0411x; 1.0411x over previous
//
#include <hip/hip_runtime.h>
#include <hip/hip_bf16.h>

// ExplodedLogit: out (512, 1 + 512*512) fp32.
//   scores = x @ W.T + b            (512,)
//   idx    = argmax(scores)
//   out[i][0]             = scores[i]
//   out[i][1 + r*512 + j] = scores[i] * (j==idx ? MASK_VAL : 1.0f)
// Output = 537 MB fp32 -> HBM-write-bound, roofline ~85 us @ 6.3 TB/s.
// R3: plain (non-NT) float4 stores — harness memset hits 6.26 TB/s with
// plain stores; NT stores suspected cause of fill running at ~2.7 TB/s.
// Also BPR 32->16: fewer blocks, 16 store-iters each (less block churn).

#define TRACKS 512
#define FEATURES 256
#define ROWSTRIDE 262145LL          // 1 + 512*512
#define BULK 262144                 // 512*512
#define MASK_VAL (-105.918914f)     // float32(log(1e-46))

#define BPR 16                      // blocks per row in fill kernel
#define CHUNK (BULK / BPR)          // 16384 elements per block

typedef float vf4 __attribute__((ext_vector_type(4)));

// ---- kernel 1: one wave per row dot-product ----
__global__ __launch_bounds__(64) void scores_kernel(
    const float* __restrict__ x, const float* __restrict__ W,
    const float* __restrict__ b, float* __restrict__ scores) {
  int row = blockIdx.x;
  int lane = threadIdx.x;  // 0..63
  const float4* xr = (const float4*)(x + row * FEATURES);
  const float4* wr = (const float4*)W;
  float4 xv = xr[lane];
  float4 wv = wr[lane];
  float s = xv.x * wv.x + xv.y * wv.y + xv.z * wv.z + xv.w * wv.w;
#pragma unroll
  for (int off = 32; off; off >>= 1) s += __shfl_down(s, off);
  if (lane == 0) scores[row] = s + b[0];
}

// ---- kernel 2: argmax (first-index tie-break) + column-0 writes ----
__global__ __launch_bounds__(512) void argmax_kernel(
    const float* __restrict__ scores, int* __restrict__ idx_out,
    float* __restrict__ out) {
  __shared__ float svals[TRACKS];
  __shared__ int sidx[TRACKS];
  int t = threadIdx.x;
  float v = scores[t];
  out[(long long)t * ROWSTRIDE] = v;  // out[i][0] = scores[i]
  svals[t] = v;
  sidx[t] = t;
  __syncthreads();
  for (int off = 256; off; off >>= 1) {
    if (t < off) {
      float v2 = svals[t + off];
      int i2 = sidx[t + off];
      if (v2 > svals[t] || (v2 == svals[t] && i2 < sidx[t])) {
        svals[t] = v2;
        sidx[t] = i2;
      }
    }
    __syncthreads();
  }
  if (t == 0) idx_out[0] = sidx[0];
}

// ---- kernel 3: the 537 MB stream-out ----
// Each block covers CHUNK contiguous elements of one row's bulk region.
// A thread's float4 stores stride by 1024 elements == 0 mod 512 (pattern
// period), so its float4 value is loop-invariant: compute once, store 16x.
__global__ __launch_bounds__(256) void fill_kernel(
    const float* __restrict__ scores, const int* __restrict__ idxp,
    float* __restrict__ out) {
  int row = blockIdx.x / BPR;
  int blk = blockIdx.x % BPR;
  int t = threadIdx.x;

  float s = scores[row];
  int idx = *idxp;
  float sm = s * MASK_VAL;

  long long S = (long long)row * ROWSTRIDE + 1;  // bulk start (global elems)
  long long lo = S + (long long)blk * CHUNK;

  // scalar head to reach 16B alignment (row stride is odd)
  int align = (int)((4 - (lo & 3)) & 3);
  if (t < align) {
    long long p = lo + t;
    int j = (int)((p - S) & 511);
    out[p] = (j == idx) ? sm : s;
  }

  int nrem = CHUNK - align;
  int nf4 = nrem >> 2;
  int tail = nrem & 3;
  long long abase = lo + align;  // 16B-aligned element offset

  // loop-invariant float4 for this thread
  int j0 = (int)((abase - S + 4 * t) & 511);
  vf4 val;
  val.x = (j0 == idx) ? sm : s;
  val.y = (((j0 + 1) & 511) == idx) ? sm : s;
  val.z = (((j0 + 2) & 511) == idx) ? sm : s;
  val.w = (((j0 + 3) & 511) == idx) ? sm : s;

  vf4* outv = (vf4*)(out + abase);
  for (int k = t; k < nf4; k += 256) {
    outv[k] = val;
  }

  // scalar tail
  if (t < tail) {
    long long p = abase + 4LL * nf4 + t;
    int j = (int)((p - S) & 511);
    out[p] = (j == idx) ? sm : s;
  }
}

extern "C" void kernel_launch(void* const* d_in, const int* in_sizes, int n_in,
                              void* d_out, int out_size, void* d_ws,
                              size_t ws_size, hipStream_t stream) {
  const float* x = (const float*)d_in[0];
  const float* W = (const float*)d_in[1];
  const float* b = (const float*)d_in[2];
  float* out = (float*)d_out;

  float* scores = (float*)d_ws;              // 512 floats
  int* idx = (int*)((float*)d_ws + TRACKS);  // 1 int

  scores_kernel<<<TRACKS, 64, 0, stream>>>(x, W, b, scores);
  argmax_kernel<<<1, TRACKS, 0, stream>>>(scores, idx, out);
  fill_kernel<<<TRACKS * BPR, 256, 0, stream>>>(scores, idx, out);
}